// Round 11
// baseline (90.669 us; speedup 1.0000x reference)
//
#include <hip/hip_runtime.h>

#define NTH    200          // number of thresholds
#define NBINS  201          // count values g in [0,200]
#define NBLKH  2048         // hist grid: 8 blocks/CU = 32 waves/CU (max TLP)
#define HTPB   256          // hist threads/block = 4 waves
#define HWAVES 4

// Kernel 1: per-wave LDS histograms of g = #{k : th[k] < p} (lower_bound),
// one packed (label<<16 | 1) LDS atomic per element. Branchless binning:
// k0 = (int)(p*199) errs by <1 bin; since th is monotone,
//   g = k0 + (th[k0] < p) + (th[k0+1] < p)   — exact.
// Labels are guaranteed 0/1 -> add = 1 | (label<<16).
// Block writes 201 packed totals (pos<<16 | neg, each <= 2048) TRANSPOSED:
// part[bin*NBLKH + b], plain stores (no memset / global atomics; kernel
// boundary provides coherence). 2048 blocks: per-thread work is ~2 float4
// iterations; latency hiding comes from 32 waves/CU TLP.
__global__ void __launch_bounds__(HTPB)
auroc_hist_kernel(const float* __restrict__ preds,
                  const int*   __restrict__ labels,
                  const float* __restrict__ thresholds,
                  unsigned int* __restrict__ part,   // [NBINS][NBLKH]
                  int n) {
    __shared__ float        s_th[NTH];
    __shared__ unsigned int s_hist[HWAVES][NBINS];

    const int t    = threadIdx.x;
    const int wave = t >> 6;

    for (int i = t; i < NTH; i += HTPB)
        s_th[i] = thresholds[i];
    for (int i = t; i < HWAVES * NBINS; i += HTPB)
        ((unsigned int*)s_hist)[i] = 0u;
    __syncthreads();

    unsigned int* my = s_hist[wave];

    const int gid = blockIdx.x * HTPB + t;
    const int S   = gridDim.x * HTPB;
    const int n4  = n >> 2;
    const float4* p4 = (const float4*)preds;
    const int4*   l4 = (const int4*)labels;

    for (int i = gid; i < n4; i += S) {
        float4 p = p4[i];
        int4   l = l4[i];
        float pv[4] = {p.x, p.y, p.z, p.w};
        int   lv[4] = {l.x, l.y, l.z, l.w};
#pragma unroll
        for (int j = 0; j < 4; ++j) {
            float pp = pv[j];
            int k0 = (int)(pp * 199.0f);          // pp >= 0
            k0 = k0 > 198 ? 198 : k0;
            float ta = s_th[k0];                  // adjacent -> ds_read2_b32
            float tb = s_th[k0 + 1];
            int g = k0 + (ta < pp) + (tb < pp);   // monotone thresholds
            unsigned int add = 1u | ((unsigned int)lv[j] << 16);
            atomicAdd(&my[g], add);
        }
    }
    for (int k = (n4 << 2) + gid; k < n; k += S) {   // scalar tail
        float pp = preds[k];
        int k0 = (int)(pp * 199.0f);
        k0 = k0 > 198 ? 198 : k0;
        float ta = s_th[k0];
        float tb = s_th[k0 + 1];
        int g = k0 + (ta < pp) + (tb < pp);
        unsigned int add = 1u | ((unsigned int)labels[k] << 16);
        atomicAdd(&my[g], add);
    }
    __syncthreads();

    // Combine 4 wave copies (block handles <= 2048 elems: no field carry),
    // store this block's 201 packed bin totals.
    const int b = blockIdx.x;
    for (int i2 = t; i2 < NBINS; i2 += HTPB) {
        unsigned int v = s_hist[0][i2] + s_hist[1][i2] + s_hist[2][i2] + s_hist[3][i2];
        unsigned int pos = v >> 16;
        unsigned int neg = (v & 0xFFFFu) - pos;
        part[i2 * NBLKH + b] = (pos << 16) | neg;
    }
}

// Kernel 2: row reduction spread across CUs. Block r sums its row's 2048
// packed words (two uint4 per thread, coalesced), unpacks pos/neg during
// accumulation (sums <= 2048*2048 < 2^32), shuffle-reduces, plain stores.
__global__ void __launch_bounds__(256)
auroc_reduce_kernel(const unsigned int* __restrict__ part,  // [NBINS][NBLKH]
                    unsigned int* __restrict__ g_pos,       // [NBINS]
                    unsigned int* __restrict__ g_neg) {     // [NBINS]
    __shared__ unsigned int s_w[HWAVES][2];

    const int t = threadIdx.x;
    const int r = blockIdx.x;

    const uint4* row = (const uint4*)(part + r * NBLKH);
    uint4 v0 = row[t];
    uint4 v1 = row[t + 256];
    unsigned int ap = (v0.x >> 16) + (v0.y >> 16) + (v0.z >> 16) + (v0.w >> 16)
                    + (v1.x >> 16) + (v1.y >> 16) + (v1.z >> 16) + (v1.w >> 16);
    unsigned int an = (v0.x & 0xFFFFu) + (v0.y & 0xFFFFu)
                    + (v0.z & 0xFFFFu) + (v0.w & 0xFFFFu)
                    + (v1.x & 0xFFFFu) + (v1.y & 0xFFFFu)
                    + (v1.z & 0xFFFFu) + (v1.w & 0xFFFFu);
#pragma unroll
    for (int off = 32; off >= 1; off >>= 1) {
        ap += __shfl_down(ap, off, 64);
        an += __shfl_down(an, off, 64);
    }
    if ((t & 63) == 0) { s_w[t >> 6][0] = ap; s_w[t >> 6][1] = an; }
    __syncthreads();

    if (t == 0) {
        g_pos[r] = s_w[0][0] + s_w[1][0] + s_w[2][0] + s_w[3][0];
        g_neg[r] = s_w[0][1] + s_w[1][1] + s_w[2][1] + s_w[3][1];
    }
}

// Kernel 3: one block reads 402 words -> suffix sums -> FPR/TPR -> AUC.
__global__ void __launch_bounds__(256)
auroc_finish_kernel(const unsigned int* __restrict__ g_pos,  // [NBINS]
                    const unsigned int* __restrict__ g_neg,  // [NBINS]
                    float* __restrict__ out) {
    __shared__ unsigned int s_pos[NBINS], s_neg[NBINS];
    __shared__ unsigned int s_sufp[NBINS + 1], s_sufn[NBINS + 1];
    __shared__ float s_x[NTH], s_y[NTH];

    const int t = threadIdx.x;

    if (t < NBINS) { s_pos[t] = g_pos[t]; s_neg[t] = g_neg[t]; }
    if (t == 0)    { s_sufp[NBINS] = 0u; s_sufn[NBINS] = 0u; }
    __syncthreads();

    if (t < NBINS) {
        unsigned int sp = 0u, sn = 0u;
        for (int k = t; k < NBINS; ++k) { sp += s_pos[k]; sn += s_neg[k]; }
        s_sufp[t] = sp;
        s_sufn[t] = sn;
    }
    __syncthreads();

    const float P   = (float)s_sufp[0];
    const float Nn  = (float)s_sufn[0];
    const float EPS = 1e-6f;

    if (t < NTH) {
        float tp = (float)s_sufp[t + 1];   // p > th[t] <=> g >= t+1
        float fp = (float)s_sufn[t + 1];
        float fn = P - tp;
        float tn = Nn - fp;
        s_y[t] = (tp + EPS) / (tp + fn + EPS);   // TPR
        s_x[t] = fp / (fp + tn + EPS);           // FPR
    }
    __syncthreads();

    if (t == 0) {
        double auc = 0.0;
        for (int i = 0; i < NTH - 1; ++i)
            auc += (double)((s_x[i] - s_x[i + 1]) * (s_y[i] + s_y[i + 1]) * 0.5f);
        out[0] = (float)auc;
    }
}

extern "C" void kernel_launch(void* const* d_in, const int* in_sizes, int n_in,
                              void* d_out, int out_size, void* d_ws, size_t ws_size,
                              hipStream_t stream) {
    const float* preds      = (const float*)d_in[0];
    const int*   labels     = (const int*)d_in[1];
    const float* thresholds = (const float*)d_in[2];
    float*       out        = (float*)d_out;
    unsigned int* part      = (unsigned int*)d_ws;    // 201*2048 u32 = 1.65 MB
    unsigned int* g_pos     = part + NBINS * NBLKH;   // 201
    unsigned int* g_neg     = g_pos + NBINS;          // 201

    const int n = in_sizes[0];

    auroc_hist_kernel<<<NBLKH, HTPB, 0, stream>>>(preds, labels, thresholds,
                                                  part, n);
    auroc_reduce_kernel<<<NBINS, 256, 0, stream>>>(part, g_pos, g_neg);
    auroc_finish_kernel<<<1, 256, 0, stream>>>(g_pos, g_neg, out);
}

// Round 12
// 88.318 us; speedup vs baseline: 1.0266x; 1.0266x over previous
//
#include <hip/hip_runtime.h>

#define NTH    200          // number of thresholds
#define NBINS  201          // count values g in [0,200]
#define NBLKH  1024         // hist grid: 4 blocks/CU (R10-proven best)
#define HTPB   256          // hist threads/block = 4 waves
#define HWAVES 4

// Kernel 1: per-wave LDS histograms of g = #{k : th[k] < p} (lower_bound),
// one packed (label<<16 | 1) LDS atomic per element. Branchless binning:
// k0 = (int)(p*199) errs by <1 bin; th monotone =>
//   g = k0 + (th[k0] < p) + (th[k0+1] < p)   — exact.
// float2 LUT s_lut[k] = (th[k], th[k+1]) -> ONE ds_read_b64 per element.
// Labels guaranteed 0/1 -> add = 1 | (label<<16).
// Block writes 201 packed totals (pos<<16 | neg, each <= 4096) TRANSPOSED:
// part[bin*NBLKH + b], plain stores (no memset / global atomics; kernel
// boundary provides coherence).
__global__ void __launch_bounds__(HTPB)
auroc_hist_kernel(const float* __restrict__ preds,
                  const int*   __restrict__ labels,
                  const float* __restrict__ thresholds,
                  unsigned int* __restrict__ part,   // [NBINS][NBLKH]
                  int n) {
    __shared__ float2       s_lut[NTH - 1];   // 199 pairs (th[k], th[k+1])
    __shared__ unsigned int s_hist[HWAVES][NBINS];

    const int t    = threadIdx.x;
    const int wave = t >> 6;

    if (t < NTH - 1) {
        float2 v;
        v.x = thresholds[t];
        v.y = thresholds[t + 1];
        s_lut[t] = v;
    }
    for (int i = t; i < HWAVES * NBINS; i += HTPB)
        ((unsigned int*)s_hist)[i] = 0u;
    __syncthreads();

    unsigned int* my = s_hist[wave];

    const int gid = blockIdx.x * HTPB + t;
    const int S   = gridDim.x * HTPB;
    const int n4  = n >> 2;
    const float4* p4 = (const float4*)preds;
    const int4*   l4 = (const int4*)labels;

    int i = gid;
    // 2-way batch: 4 independent 16B loads in flight per thread.
    for (; i + S < n4; i += 2 * S) {
        float4 pa = p4[i];
        int4   la = l4[i];
        float4 pb = p4[i + S];
        int4   lb = l4[i + S];

        float pv[8] = {pa.x, pa.y, pa.z, pa.w, pb.x, pb.y, pb.z, pb.w};
        int   lv[8] = {la.x, la.y, la.z, la.w, lb.x, lb.y, lb.z, lb.w};
#pragma unroll
        for (int j = 0; j < 8; ++j) {
            float pp = pv[j];
            int k0 = (int)(pp * 199.0f);          // pp >= 0
            k0 = k0 > 198 ? 198 : k0;
            float2 th2 = s_lut[k0];               // one ds_read_b64
            int g = k0 + (th2.x < pp) + (th2.y < pp);
            unsigned int add = 1u | ((unsigned int)lv[j] << 16);
            atomicAdd(&my[g], add);
        }
    }
    for (; i < n4; i += S) {                      // vector remainder
        float4 p = p4[i];
        int4   l = l4[i];
        float pv[4] = {p.x, p.y, p.z, p.w};
        int   lv[4] = {l.x, l.y, l.z, l.w};
#pragma unroll
        for (int j = 0; j < 4; ++j) {
            float pp = pv[j];
            int k0 = (int)(pp * 199.0f);
            k0 = k0 > 198 ? 198 : k0;
            float2 th2 = s_lut[k0];
            int g = k0 + (th2.x < pp) + (th2.y < pp);
            unsigned int add = 1u | ((unsigned int)lv[j] << 16);
            atomicAdd(&my[g], add);
        }
    }
    for (int k = (n4 << 2) + gid; k < n; k += S) {   // scalar tail
        float pp = preds[k];
        int k0 = (int)(pp * 199.0f);
        k0 = k0 > 198 ? 198 : k0;
        float2 th2 = s_lut[k0];
        int g = k0 + (th2.x < pp) + (th2.y < pp);
        unsigned int add = 1u | ((unsigned int)labels[k] << 16);
        atomicAdd(&my[g], add);
    }
    __syncthreads();

    // Combine 4 wave copies (block handles <= 4096 elems: no field carry),
    // store this block's 201 packed bin totals.
    const int b = blockIdx.x;
    for (int i2 = t; i2 < NBINS; i2 += HTPB) {
        unsigned int v = s_hist[0][i2] + s_hist[1][i2] + s_hist[2][i2] + s_hist[3][i2];
        unsigned int pos = v >> 16;
        unsigned int neg = (v & 0xFFFFu) - pos;
        part[i2 * NBLKH + b] = (pos << 16) | neg;
    }
}

// Kernel 2: row reduction spread across CUs. Block r sums its row's 1024
// packed words (one uint4 per thread, coalesced), unpacks pos/neg during
// accumulation, shuffle-reduces, plain-stores g_pos[r], g_neg[r].
__global__ void __launch_bounds__(256)
auroc_reduce_kernel(const unsigned int* __restrict__ part,  // [NBINS][NBLKH]
                    unsigned int* __restrict__ g_pos,       // [NBINS]
                    unsigned int* __restrict__ g_neg) {     // [NBINS]
    __shared__ unsigned int s_w[HWAVES][2];

    const int t = threadIdx.x;
    const int r = blockIdx.x;

    uint4 v = ((const uint4*)(part + r * NBLKH))[t];
    unsigned int ap = (v.x >> 16) + (v.y >> 16) + (v.z >> 16) + (v.w >> 16);
    unsigned int an = (v.x & 0xFFFFu) + (v.y & 0xFFFFu) +
                      (v.z & 0xFFFFu) + (v.w & 0xFFFFu);
#pragma unroll
    for (int off = 32; off >= 1; off >>= 1) {
        ap += __shfl_down(ap, off, 64);
        an += __shfl_down(an, off, 64);
    }
    if ((t & 63) == 0) { s_w[t >> 6][0] = ap; s_w[t >> 6][1] = an; }
    __syncthreads();

    if (t == 0) {
        g_pos[r] = s_w[0][0] + s_w[1][0] + s_w[2][0] + s_w[3][0];
        g_neg[r] = s_w[0][1] + s_w[1][1] + s_w[2][1] + s_w[3][1];
    }
}

// Kernel 3: one block reads 402 words -> suffix sums -> FPR/TPR -> AUC.
__global__ void __launch_bounds__(256)
auroc_finish_kernel(const unsigned int* __restrict__ g_pos,  // [NBINS]
                    const unsigned int* __restrict__ g_neg,  // [NBINS]
                    float* __restrict__ out) {
    __shared__ unsigned int s_pos[NBINS], s_neg[NBINS];
    __shared__ unsigned int s_sufp[NBINS + 1], s_sufn[NBINS + 1];
    __shared__ float s_x[NTH], s_y[NTH];

    const int t = threadIdx.x;

    if (t < NBINS) { s_pos[t] = g_pos[t]; s_neg[t] = g_neg[t]; }
    if (t == 0)    { s_sufp[NBINS] = 0u; s_sufn[NBINS] = 0u; }
    __syncthreads();

    if (t < NBINS) {
        unsigned int sp = 0u, sn = 0u;
        for (int k = t; k < NBINS; ++k) { sp += s_pos[k]; sn += s_neg[k]; }
        s_sufp[t] = sp;
        s_sufn[t] = sn;
    }
    __syncthreads();

    const float P   = (float)s_sufp[0];
    const float Nn  = (float)s_sufn[0];
    const float EPS = 1e-6f;

    if (t < NTH) {
        float tp = (float)s_sufp[t + 1];   // p > th[t] <=> g >= t+1
        float fp = (float)s_sufn[t + 1];
        float fn = P - tp;
        float tn = Nn - fp;
        s_y[t] = (tp + EPS) / (tp + fn + EPS);   // TPR
        s_x[t] = fp / (fp + tn + EPS);           // FPR
    }
    __syncthreads();

    if (t == 0) {
        double auc = 0.0;
        for (int i = 0; i < NTH - 1; ++i)
            auc += (double)((s_x[i] - s_x[i + 1]) * (s_y[i] + s_y[i + 1]) * 0.5f);
        out[0] = (float)auc;
    }
}

extern "C" void kernel_launch(void* const* d_in, const int* in_sizes, int n_in,
                              void* d_out, int out_size, void* d_ws, size_t ws_size,
                              hipStream_t stream) {
    const float* preds      = (const float*)d_in[0];
    const int*   labels     = (const int*)d_in[1];
    const float* thresholds = (const float*)d_in[2];
    float*       out        = (float*)d_out;
    unsigned int* part      = (unsigned int*)d_ws;    // 201*1024 u32 = 823 KB
    unsigned int* g_pos     = part + NBINS * NBLKH;   // 201
    unsigned int* g_neg     = g_pos + NBINS;          // 201

    const int n = in_sizes[0];

    auroc_hist_kernel<<<NBLKH, HTPB, 0, stream>>>(preds, labels, thresholds,
                                                  part, n);
    auroc_reduce_kernel<<<NBINS, 256, 0, stream>>>(part, g_pos, g_neg);
    auroc_finish_kernel<<<1, 256, 0, stream>>>(g_pos, g_neg, out);
}